// Round 2
// baseline (404.614 us; speedup 1.0000x reference)
//
#include <hip/hip_runtime.h>

#define BB 4
#define DD 4096
#define FF 128
#define SLOPE 0.2f

typedef float f32x4 __attribute__((ext_vector_type(4)));
typedef short bf16x8 __attribute__((ext_vector_type(8)));

__device__ __forceinline__ unsigned short f2bf(float v) {
  union { float f; unsigned u; } c; c.f = v;
  unsigned r = c.u + 0x7FFFu + ((c.u >> 16) & 1u);
  return (unsigned short)(r >> 16);
}
__device__ __forceinline__ float bf2f(unsigned short u) {
  union { unsigned u; float f; } c; c.u = ((unsigned)u) << 16;
  return c.f;
}

// Kernel A: Wh = x@W (f32 regs) -> WhT bf16 [B][F][D]; fs, ft (f32); mb[b] = max(0, max_j ft)
__global__ __launch_bounds__(256) void kA(
    const float* __restrict__ x, const float* __restrict__ W,
    const float* __restrict__ a_src, const float* __restrict__ a_tgt,
    unsigned short* __restrict__ WhT, float* __restrict__ fs,
    float* __restrict__ ft, int* __restrict__ mb)
{
  __shared__ __align__(16) float Ws[128 * 128];
  __shared__ __align__(16) float xs[64 * 128];     // reused as reduction scratch
  __shared__ unsigned short st[128 * 66];
  const int t = threadIdx.x;
  const int wg = blockIdx.x;            // 256 wgs x 64 rows
  const int row0 = wg * 64;             // flat row in [0, B*D)
  const int b = row0 / DD;
  const int i_in_b = row0 % DD;

  for (int i = t * 4; i < 128 * 128; i += 1024)
    *(float4*)&Ws[i] = *(const float4*)&W[i];
  for (int i = t * 4; i < 64 * 128; i += 1024)
    *(float4*)&xs[i] = *(const float4*)&x[(size_t)row0 * FF + i];
  __syncthreads();

  const int fg = t & 31, rg = t >> 5;
  const int f0 = fg * 4, r0 = rg * 8;
  float acc[8][4];
  #pragma unroll
  for (int a = 0; a < 8; ++a) acc[a][0] = acc[a][1] = acc[a][2] = acc[a][3] = 0.f;
  for (int k = 0; k < 128; ++k) {
    float4 wq = *(const float4*)&Ws[k * 128 + f0];
    #pragma unroll
    for (int rr = 0; rr < 8; ++rr) {
      float xv = xs[(r0 + rr) * 128 + k];
      acc[rr][0] += xv * wq.x; acc[rr][1] += xv * wq.y;
      acc[rr][2] += xv * wq.z; acc[rr][3] += xv * wq.w;
    }
  }
  __syncthreads();   // done reading xs; reuse as reduction scratch
  float* red_s = xs;             // [64][33]
  float* red_t = xs + 64 * 33;   // [64][33]
  float4 as4 = *(const float4*)&a_src[f0];
  float4 at4 = *(const float4*)&a_tgt[f0];
  #pragma unroll
  for (int rr = 0; rr < 8; ++rr) {
    float ps = acc[rr][0]*as4.x + acc[rr][1]*as4.y + acc[rr][2]*as4.z + acc[rr][3]*as4.w;
    float pt = acc[rr][0]*at4.x + acc[rr][1]*at4.y + acc[rr][2]*at4.z + acc[rr][3]*at4.w;
    red_s[(r0 + rr) * 33 + fg] = ps;
    red_t[(r0 + rr) * 33 + fg] = pt;
    st[(f0 + 0) * 66 + r0 + rr] = f2bf(acc[rr][0]);
    st[(f0 + 1) * 66 + r0 + rr] = f2bf(acc[rr][1]);
    st[(f0 + 2) * 66 + r0 + rr] = f2bf(acc[rr][2]);
    st[(f0 + 3) * 66 + r0 + rr] = f2bf(acc[rr][3]);
  }
  __syncthreads();
  if (t < 64) {
    float s = 0.f, tt = 0.f;
    #pragma unroll
    for (int q = 0; q < 32; ++q) { s += red_s[t * 33 + q]; tt += red_t[t * 33 + q]; }
    fs[row0 + t] = s;
    ft[row0 + t] = tt;
    float m = fmaxf(0.f, tt);
    #pragma unroll
    for (int s2 = 1; s2 < 64; s2 <<= 1) m = fmaxf(m, __shfl_xor(m, s2));
    if (t == 0) atomicMax(&mb[b], __float_as_int(m));  // m >= 0: int-order == float-order
  }
  // WhT bf16 writeout (coalesced per 64-wide row chunks)
  for (int p = 0; p < 32; ++p) {
    int idx = p * 256 + t;
    int f = idx >> 6, rl = idx & 63;
    WhT[((size_t)b * FF + f) * DD + i_in_b + rl] = st[f * 66 + rl];
  }
}

// Kernel C: fused scores + softmax + attn write + PV MFMA.
// 8 rows / wg, 8 waves, 64 KB LDS -> 2 wg/CU for phase overlap across wgs.
__global__ __launch_bounds__(512) void kC(
    const int* __restrict__ adj, const float* __restrict__ fs,
    const float* __restrict__ ft, const int* __restrict__ mbp,
    const unsigned short* __restrict__ WhT, const float* __restrict__ bias,
    float* __restrict__ hout, float* __restrict__ attn)
{
  __shared__ __align__(16) unsigned short p_lds[8 * 4096];  // 64 KB, XOR-swizzled
  __shared__ float sums[8];
  __shared__ float invs[8];
  const int t = threadIdx.x;
  const int w = t >> 6, l = t & 63;
  const int bid = blockIdx.x;
  const int b = bid >> 9;               // 512 wgs per batch
  const int i0 = (bid & 511) << 3;      // 8 rows per wg
  const float mbv = __int_as_float(mbp[b]);   // >= 0, upper bound of ft
  const int r = w;                      // 1 row per wave in phase 1/2a
  const float fsr = fs[b * DD + i0 + r];
  const float M = fmaxf(0.f, fsr + mbv);      // >= row max of e (lrelu monotone)
  const float* ftb = ft + b * DD;
  const int* adjr = adj + ((size_t)b * DD + i0 + r) * DD;
  const unsigned sw = (unsigned)(r & 7) << 4;
  float sum = 0.f;

  auto pf = [](float fsv, float ftv, int av, float Mv) {
    float e = fsv + ftv;
    e = e > 0.f ? e : SLOPE * e;   // leaky_relu
    e = av ? e : 0.f;              // masked scores become 0 (NOT -inf)
    return __expf(e - Mv);
  };

  // Phase 1: stream adj (1 row per wave), compute p, stash bf16 p in LDS, row sum
  #pragma unroll 2
  for (int c = 0; c < DD; c += 256) {
    const int j = c + l * 4;
    float4 f4 = *(const float4*)(ftb + j);
    int4 a0 = *(const int4*)(adjr + j);
    float p0 = pf(fsr, f4.x, a0.x, M), p1 = pf(fsr, f4.y, a0.y, M);
    float p2 = pf(fsr, f4.z, a0.z, M), p3 = pf(fsr, f4.w, a0.w, M);
    sum += (p0 + p1) + (p2 + p3);
    ushort4 q; q.x = f2bf(p0); q.y = f2bf(p1); q.z = f2bf(p2); q.w = f2bf(p3);
    unsigned o = (((unsigned)r * 8192u) + (unsigned)j * 2u) ^ sw;
    *(ushort4*)&p_lds[o >> 1] = q;
  }
  #pragma unroll
  for (int s = 1; s < 64; s <<= 1) sum += __shfl_xor(sum, s);
  if (l == 0) sums[r] = sum;
  __syncthreads();
  if (t < 8) invs[t] = 1.0f / sums[t];
  __syncthreads();

  // Phase 2a: write normalized attn (1 row per wave; stores overlap MFMA below)
  {
    const float iv = invs[r];
    float* arow = attn + (size_t)b * DD * DD + (size_t)(i0 + r) * DD;
    #pragma unroll 2
    for (int it = 0; it < 8; ++it) {
      const int j = it * 512 + l * 8;
      unsigned o = (((unsigned)r * 8192u) + (unsigned)j * 2u) ^ sw;
      ushort4 q0 = *(const ushort4*)&p_lds[o >> 1];
      ushort4 q1 = *(const ushort4*)&p_lds[(o >> 1) + 4];
      float4 v0, v1;
      v0.x = bf2f(q0.x) * iv; v0.y = bf2f(q0.y) * iv; v0.z = bf2f(q0.z) * iv; v0.w = bf2f(q0.w) * iv;
      v1.x = bf2f(q1.x) * iv; v1.y = bf2f(q1.y) * iv; v1.z = bf2f(q1.z) * iv; v1.w = bf2f(q1.w) * iv;
      float* dst = arow + j;
      *(float4*)dst = v0;
      *(float4*)(dst + 4) = v1;
    }
  }

  // Phase 2b: PV via mfma_f32_16x16x32_bf16. Wave w -> f-tile f0=16w, rows i0..i0+7.
  // A rows 8..15 read duplicate LDS rows (junk) -> pollute only C rows 8..15 (discarded).
  const int f0 = w * 16;
  const int c15 = l & 15;       // B/D column (f); A row = c15&7
  const int a_row = c15 & 7;
  const int kg = l >> 4;
  const unsigned abase = (unsigned)a_row * 8192u + (unsigned)kg * 16u;
  const unsigned asw = (unsigned)a_row << 4;
  const unsigned short* wrow = WhT + ((size_t)b * FF + f0 + c15) * DD + kg * 8;
  f32x4 acc0 = {0.f, 0.f, 0.f, 0.f}, acc1 = {0.f, 0.f, 0.f, 0.f};
  for (int ks = 0; ks < 128; ks += 2) {
    unsigned ao0 = (abase + (unsigned)ks * 64u) ^ asw;
    unsigned ao1 = (abase + (unsigned)(ks + 1) * 64u) ^ asw;
    bf16x8 A0 = *(const bf16x8*)&p_lds[ao0 >> 1];
    bf16x8 A1 = *(const bf16x8*)&p_lds[ao1 >> 1];
    bf16x8 B0 = *(const bf16x8*)&wrow[(size_t)ks * 32];
    bf16x8 B1 = *(const bf16x8*)&wrow[(size_t)(ks + 1) * 32];
    acc0 = __builtin_amdgcn_mfma_f32_16x16x32_bf16(A0, B0, acc0, 0, 0, 0);
    acc1 = __builtin_amdgcn_mfma_f32_16x16x32_bf16(A1, B1, acc1, 0, 0, 0);
  }
  f32x4 acc = acc0 + acc1;
  if (kg < 2) {                 // C/D rows kg*4+q in 0..7 are the real ones
    const float bv = bias[f0 + c15];
    #pragma unroll
    for (int q = 0; q < 4; ++q) {
      int orow = kg * 4 + q;    // C/D: row = (lane>>4)*4 + reg
      float val = acc[q] * invs[orow] + bv;
      hout[((size_t)b * DD + i0 + orow) * FF + f0 + c15] = val;
    }
  }
}

extern "C" void kernel_launch(void* const* d_in, const int* in_sizes, int n_in,
                              void* d_out, int out_size, void* d_ws, size_t ws_size,
                              hipStream_t stream) {
  const float* x     = (const float*)d_in[0];
  const int*   adj   = (const int*)d_in[1];
  const float* W     = (const float*)d_in[2];
  const float* a_src = (const float*)d_in[3];
  const float* a_tgt = (const float*)d_in[4];
  const float* bias  = (const float*)d_in[5];
  char* ws = (char*)d_ws;
  unsigned short* WhT = (unsigned short*)ws;            // 4 MB
  float* fs = (float*)(ws + 4194304);                   // 64 KB
  float* ft = (float*)(ws + 4259840);                   // 64 KB
  int*   mb = (int*)(ws + 4325376);                     // 16 B
  float* hout = (float*)d_out;                          // [B][D][F]
  float* attn = hout + (size_t)BB * DD * FF;            // [B][D][D]
  (void)hipMemsetAsync(mb, 0, BB * sizeof(int), stream);
  kA<<<256, 256, 0, stream>>>(x, W, a_src, a_tgt, WhT, fs, ft, mb);
  kC<<<2048, 512, 0, stream>>>(adj, fs, ft, mb, WhT, bias, hout, attn);
}

// Round 3
// 292.467 us; speedup vs baseline: 1.3835x; 1.3835x over previous
//
#include <hip/hip_runtime.h>

#define BB 4
#define DD 4096
#define FF 128
#define SLOPE 0.2f

typedef float f32x4 __attribute__((ext_vector_type(4)));
typedef short bf16x8 __attribute__((ext_vector_type(8)));

__device__ __forceinline__ unsigned short f2bf(float v) {
  union { float f; unsigned u; } c; c.f = v;
  unsigned r = c.u + 0x7FFFu + ((c.u >> 16) & 1u);
  return (unsigned short)(r >> 16);
}

// Kernel A: Wh = x@W (f32 regs) -> WhT bf16 [B][F][D]; fs, ft (f32); mb[b] = max(0, max_j ft)
__global__ __launch_bounds__(256) void kA(
    const float* __restrict__ x, const float* __restrict__ W,
    const float* __restrict__ a_src, const float* __restrict__ a_tgt,
    unsigned short* __restrict__ WhT, float* __restrict__ fs,
    float* __restrict__ ft, int* __restrict__ mb)
{
  __shared__ __align__(16) float Ws[128 * 128];
  __shared__ __align__(16) float xs[64 * 128];     // reused as reduction scratch
  __shared__ unsigned short st[128 * 66];
  const int t = threadIdx.x;
  const int wg = blockIdx.x;            // 256 wgs x 64 rows
  const int row0 = wg * 64;             // flat row in [0, B*D)
  const int b = row0 / DD;
  const int i_in_b = row0 % DD;

  for (int i = t * 4; i < 128 * 128; i += 1024)
    *(float4*)&Ws[i] = *(const float4*)&W[i];
  for (int i = t * 4; i < 64 * 128; i += 1024)
    *(float4*)&xs[i] = *(const float4*)&x[(size_t)row0 * FF + i];
  __syncthreads();

  const int fg = t & 31, rg = t >> 5;
  const int f0 = fg * 4, r0 = rg * 8;
  float acc[8][4];
  #pragma unroll
  for (int a = 0; a < 8; ++a) acc[a][0] = acc[a][1] = acc[a][2] = acc[a][3] = 0.f;
  for (int k = 0; k < 128; ++k) {
    float4 wq = *(const float4*)&Ws[k * 128 + f0];
    #pragma unroll
    for (int rr = 0; rr < 8; ++rr) {
      float xv = xs[(r0 + rr) * 128 + k];
      acc[rr][0] += xv * wq.x; acc[rr][1] += xv * wq.y;
      acc[rr][2] += xv * wq.z; acc[rr][3] += xv * wq.w;
    }
  }
  __syncthreads();   // done reading xs; reuse as reduction scratch
  float* red_s = xs;             // [64][33]
  float* red_t = xs + 64 * 33;   // [64][33]
  float4 as4 = *(const float4*)&a_src[f0];
  float4 at4 = *(const float4*)&a_tgt[f0];
  #pragma unroll
  for (int rr = 0; rr < 8; ++rr) {
    float ps = acc[rr][0]*as4.x + acc[rr][1]*as4.y + acc[rr][2]*as4.z + acc[rr][3]*as4.w;
    float pt = acc[rr][0]*at4.x + acc[rr][1]*at4.y + acc[rr][2]*at4.z + acc[rr][3]*at4.w;
    red_s[(r0 + rr) * 33 + fg] = ps;
    red_t[(r0 + rr) * 33 + fg] = pt;
    st[(f0 + 0) * 66 + r0 + rr] = f2bf(acc[rr][0]);
    st[(f0 + 1) * 66 + r0 + rr] = f2bf(acc[rr][1]);
    st[(f0 + 2) * 66 + r0 + rr] = f2bf(acc[rr][2]);
    st[(f0 + 3) * 66 + r0 + rr] = f2bf(acc[rr][3]);
  }
  __syncthreads();
  if (t < 64) {
    float s = 0.f, tt = 0.f;
    #pragma unroll
    for (int q = 0; q < 32; ++q) { s += red_s[t * 33 + q]; tt += red_t[t * 33 + q]; }
    fs[row0 + t] = s;
    ft[row0 + t] = tt;
    float m = fmaxf(0.f, tt);
    #pragma unroll
    for (int s2 = 1; s2 < 64; s2 <<= 1) m = fmaxf(m, __shfl_xor(m, s2));
    if (t == 0) atomicMax(&mb[b], __float_as_int(m));  // m >= 0: int-order == float-order
  }
  // WhT bf16 writeout (coalesced per 64-wide row chunks)
  for (int p = 0; p < 32; ++p) {
    int idx = p * 256 + t;
    int f = idx >> 6, rl = idx & 63;
    WhT[((size_t)b * FF + f) * DD + i_in_b + rl] = st[f * 66 + rl];
  }
}

// Kernel BPS: one wave per row. Streams adj once: packs to 1-bit mask [row][128 words]
// and computes rowsum = sum_j exp(e_ij - M_i). Pure streaming, no LDS, no barriers.
__global__ __launch_bounds__(256) void kBPS(
    const int* __restrict__ adj, const float* __restrict__ fs,
    const float* __restrict__ ft, const int* __restrict__ mbp,
    unsigned int* __restrict__ maskw, float* __restrict__ sums)
{
  const int t = threadIdx.x;
  const int wv = t >> 6, l = t & 63;
  const int row = blockIdx.x * 4 + wv;       // flat row in [0, B*D)
  const int b = row >> 12;
  const float fsr = fs[row];
  const float mbv = __int_as_float(mbp[b]);
  const float M = fmaxf(0.f, fsr + mbv);
  const int* arow = adj + (size_t)row * DD + l * 64;
  const float* ftl = ft + (size_t)b * DD + l * 64;
  float sum = 0.f;
  unsigned wlo = 0u, whi = 0u;
  #pragma unroll
  for (int q = 0; q < 4; ++q) {
    unsigned bits = 0u;
    #pragma unroll
    for (int u = 0; u < 4; ++u) {
      const int o = q * 16 + u * 4;
      int4 a = *(const int4*)(arow + o);
      float4 f = *(const float4*)(ftl + o);
      float e0 = fsr + f.x; e0 = e0 > 0.f ? e0 : SLOPE * e0; e0 = a.x ? e0 : 0.f;
      float e1 = fsr + f.y; e1 = e1 > 0.f ? e1 : SLOPE * e1; e1 = a.y ? e1 : 0.f;
      float e2 = fsr + f.z; e2 = e2 > 0.f ? e2 : SLOPE * e2; e2 = a.z ? e2 : 0.f;
      float e3 = fsr + f.w; e3 = e3 > 0.f ? e3 : SLOPE * e3; e3 = a.w ? e3 : 0.f;
      sum += __expf(e0 - M) + __expf(e1 - M) + __expf(e2 - M) + __expf(e3 - M);
      bits |= (a.x ? 1u : 0u) << (u * 4 + 0);
      bits |= (a.y ? 1u : 0u) << (u * 4 + 1);
      bits |= (a.z ? 1u : 0u) << (u * 4 + 2);
      bits |= (a.w ? 1u : 0u) << (u * 4 + 3);
    }
    if      (q == 0) wlo  = bits;
    else if (q == 1) wlo |= bits << 16;
    else if (q == 2) whi  = bits;
    else             whi |= bits << 16;
  }
  uint2 mv; mv.x = wlo; mv.y = whi;
  *(uint2*)(maskw + (size_t)row * 128 + l * 2) = mv;   // wave writes 512B contiguous
  #pragma unroll
  for (int s = 1; s < 64; s <<= 1) sum += __shfl_xor(sum, s);
  if (l == 0) sums[row] = sum;
}

// Kernel C: 16 rows/wg, 8 waves, 16-chunk pipeline.
// Per chunk (256 j): B-prefetch -> compute normalized p-hat (exp) -> write attn f32
// -> stash bf16 in double-buffered 8KB LDS tile -> barrier -> 8 MFMA k-steps.
__global__ __launch_bounds__(512, 4) void kC(
    const float* __restrict__ fs, const float* __restrict__ ft,
    const int* __restrict__ mbp, const unsigned int* __restrict__ maskw,
    const float* __restrict__ sums, const unsigned short* __restrict__ WhT,
    const float* __restrict__ bias, float* __restrict__ hout,
    float* __restrict__ attn)
{
  __shared__ __align__(16) unsigned short p_lds[2][16 * 256];  // 16 KB, XOR-swizzled
  __shared__ __align__(16) unsigned int mlds[16 * 128];        // 8 KB row masks
  const int t = threadIdx.x;
  const int w = t >> 6, l = t & 63;
  const int bid = blockIdx.x;
  const int b = bid >> 8;
  const int i0 = (bid & 255) << 4;
  // wave-local mask staging: wave w's threads load exactly rows 2w,2w+1
  {
    const unsigned int* msrc = maskw + (size_t)(b * DD + i0) * 128;
    *(uint4*)&mlds[t * 4] = *(const uint4*)&msrc[t * 4];
  }
  const float mbv = __int_as_float(mbp[b]);
  const int r0 = 2 * w, r1 = r0 + 1;
  const float fs0 = fs[b * DD + i0 + r0], fs1 = fs[b * DD + i0 + r1];
  const float M0 = fmaxf(0.f, fs0 + mbv), M1 = fmaxf(0.f, fs1 + mbv);
  const float inv0 = 1.0f / sums[b * DD + i0 + r0];
  const float inv1 = 1.0f / sums[b * DD + i0 + r1];
  const float* ftb = ft + (size_t)b * DD;
  float* arow0 = attn + (size_t)b * DD * DD + (size_t)(i0 + r0) * DD;
  float* arow1 = arow0 + DD;
  const unsigned sw0 = (unsigned)(r0 & 7) << 4;
  const unsigned sw1 = (unsigned)(r1 & 7) << 4;
  // MFMA lane constants
  const int f0 = w * 16;
  const int c15 = l & 15;
  const int kg = l >> 4;
  const unsigned abase = (unsigned)c15 * 512u + (unsigned)kg * 16u;
  const unsigned asw = (unsigned)(c15 & 7) << 4;
  const unsigned short* wrow = WhT + ((size_t)b * FF + f0 + c15) * DD + kg * 8;
  const int jl = l * 4;
  const unsigned mshift = (unsigned)(jl & 31);
  const unsigned w0base = (unsigned)r0 * 128u + (unsigned)(jl >> 5);
  const unsigned w1base = (unsigned)r1 * 128u + (unsigned)(jl >> 5);
  const unsigned o0 = ((unsigned)r0 * 512u + (unsigned)jl * 2u) ^ sw0;
  const unsigned o1 = ((unsigned)r1 * 512u + (unsigned)jl * 2u) ^ sw1;
  f32x4 acc0 = {0.f, 0.f, 0.f, 0.f}, acc1 = {0.f, 0.f, 0.f, 0.f};

  for (int c = 0; c < 16; ++c) {
    const int cb = c & 1;
    const int j = c * 256 + jl;
    // B prefetch for this chunk's 8 k-steps (consumed after the barrier;
    // HBM/L2 latency hides under the exp compute below)
    bf16x8 Bv[8];
    #pragma unroll
    for (int u = 0; u < 8; ++u)
      Bv[u] = *(const bf16x8*)&wrow[(size_t)(c * 8 + u) * 32];
    // compute normalized p-hat for 2 rows x 4 j
    float4 f4 = *(const float4*)(ftb + j);
    unsigned n0 = (mlds[w0base + (unsigned)c * 8u] >> mshift) & 0xFu;
    unsigned n1 = (mlds[w1base + (unsigned)c * 8u] >> mshift) & 0xFu;
    float e;
    e = fs0 + f4.x; e = e > 0.f ? e : SLOPE * e; e = (n0 & 1u) ? e : 0.f; float p00 = __expf(e - M0) * inv0;
    e = fs0 + f4.y; e = e > 0.f ? e : SLOPE * e; e = (n0 & 2u) ? e : 0.f; float p01 = __expf(e - M0) * inv0;
    e = fs0 + f4.z; e = e > 0.f ? e : SLOPE * e; e = (n0 & 4u) ? e : 0.f; float p02 = __expf(e - M0) * inv0;
    e = fs0 + f4.w; e = e > 0.f ? e : SLOPE * e; e = (n0 & 8u) ? e : 0.f; float p03 = __expf(e - M0) * inv0;
    e = fs1 + f4.x; e = e > 0.f ? e : SLOPE * e; e = (n1 & 1u) ? e : 0.f; float p10 = __expf(e - M1) * inv1;
    e = fs1 + f4.y; e = e > 0.f ? e : SLOPE * e; e = (n1 & 2u) ? e : 0.f; float p11 = __expf(e - M1) * inv1;
    e = fs1 + f4.z; e = e > 0.f ? e : SLOPE * e; e = (n1 & 4u) ? e : 0.f; float p12 = __expf(e - M1) * inv1;
    e = fs1 + f4.w; e = e > 0.f ? e : SLOPE * e; e = (n1 & 8u) ? e : 0.f; float p13 = __expf(e - M1) * inv1;
    float4 v0; v0.x = p00; v0.y = p01; v0.z = p02; v0.w = p03;
    float4 v1; v1.x = p10; v1.y = p11; v1.z = p12; v1.w = p13;
    *(float4*)(arow0 + j) = v0;
    *(float4*)(arow1 + j) = v1;
    ushort4 q0; q0.x = f2bf(p00); q0.y = f2bf(p01); q0.z = f2bf(p02); q0.w = f2bf(p03);
    ushort4 q1; q1.x = f2bf(p10); q1.y = f2bf(p11); q1.z = f2bf(p12); q1.w = f2bf(p13);
    *(ushort4*)((char*)&p_lds[cb][0] + o0) = q0;
    *(ushort4*)((char*)&p_lds[cb][0] + o1) = q1;
    __syncthreads();
    // 8 MFMA k-steps on this chunk (A from LDS, B prefetched above)
    #pragma unroll
    for (int u = 0; u < 8; ++u) {
      unsigned ao = (abase + (unsigned)u * 64u) ^ asw;
      bf16x8 A = *(const bf16x8*)((const char*)&p_lds[cb][0] + ao);
      if (u & 1) acc1 = __builtin_amdgcn_mfma_f32_16x16x32_bf16(A, Bv[u], acc1, 0, 0, 0);
      else       acc0 = __builtin_amdgcn_mfma_f32_16x16x32_bf16(A, Bv[u], acc0, 0, 0, 0);
    }
  }
  f32x4 acc = acc0 + acc1;
  const float bv = bias[f0 + c15];
  #pragma unroll
  for (int q = 0; q < 4; ++q) {
    int orow = kg * 4 + q;       // C/D: row = (lane>>4)*4 + reg
    hout[((size_t)b * DD + i0 + orow) * FF + f0 + c15] = acc[q] + bv;
  }
}

extern "C" void kernel_launch(void* const* d_in, const int* in_sizes, int n_in,
                              void* d_out, int out_size, void* d_ws, size_t ws_size,
                              hipStream_t stream) {
  const float* x     = (const float*)d_in[0];
  const int*   adj   = (const int*)d_in[1];
  const float* W     = (const float*)d_in[2];
  const float* a_src = (const float*)d_in[3];
  const float* a_tgt = (const float*)d_in[4];
  const float* bias  = (const float*)d_in[5];
  char* ws = (char*)d_ws;
  unsigned short* WhT   = (unsigned short*)ws;          // 4 MB
  float*        fs    = (float*)(ws + 4194304);         // 64 KB
  float*        ft    = (float*)(ws + 4259840);         // 64 KB
  int*          mb    = (int*)(ws + 4325376);           // 16 B
  unsigned int* maskw = (unsigned int*)(ws + 4456448);  // 8 MB
  float*        sums  = (float*)(ws + 12845056);        // 64 KB
  float* hout = (float*)d_out;                          // [B][D][F]
  float* attn = hout + (size_t)BB * DD * FF;            // [B][D][D]
  (void)hipMemsetAsync(mb, 0, BB * sizeof(int), stream);
  kA<<<256, 256, 0, stream>>>(x, W, a_src, a_tgt, WhT, fs, ft, mb);
  kBPS<<<BB * DD / 4, 256, 0, stream>>>(adj, fs, ft, mb, maskw, sums);
  kC<<<1024, 512, 0, stream>>>(fs, ft, mb, maskw, sums, WhT, bias, hout, attn);
}